// Round 11
// baseline (97.110 us; speedup 1.0000x reference)
//
#include <hip/hip_runtime.h>

#define BB 2
#define LL 16
#define CC 16
#define HH 64
#define WW 64
#define HWSZ (HH * WW)

// ws layout (floats):
//   [0, 262144)        cum2 (B, L, HW) float2                 = 1 MB
//   [262144, 2359296)  qp   (B*L, 4, HW) float4 quad-planes   = 8 MB
#define CUM2_FLOATS (BB * LL * HWSZ * 2)

// ---- prep: cumsum -> cum2; NCHW -> quad-planar transpose -> qp ----
// qp[((bl*4)+qs)*HWSZ + pix] = float4 of channels qs*4..qs*4+3 at pixel pix
// (each qs-plane is a contiguous 64 KB block: exactly what LDS staging wants)
__global__ __launch_bounds__(256) void gsp_prep(
    const float* __restrict__ flows,   // (B, L, 2, H, W)
    const float* __restrict__ images,  // (B, L, C, H, W)
    float2* __restrict__ cum2,         // (B, L, HW) float2
    float4* __restrict__ qp)           // (B*L, 4, HW) float4 quad-planes
{
    if (blockIdx.x < 32) {
        const int gid = blockIdx.x * 256 + threadIdx.x;   // 0..8191
        const int b   = gid >> 12;
        const int pix = gid & (HWSZ - 1);
        const float* fb = flows + (size_t)b * LL * 2 * HWSZ + pix;
        float vx[LL], vy[LL];
        #pragma unroll
        for (int l = 0; l < LL; ++l) {
            vx[l] = fb[(size_t)l * 2 * HWSZ];
            vy[l] = fb[(size_t)l * 2 * HWSZ + HWSZ];
        }
        #pragma unroll
        for (int l = 1; l < LL; ++l) { vx[l] += vx[l - 1]; vy[l] += vy[l - 1]; }
        float2* cb = cum2 + (size_t)b * LL * HWSZ + pix;
        #pragma unroll
        for (int l = 0; l < LL; ++l) {
            float2 v; v.x = vx[l]; v.y = vy[l];
            cb[(size_t)l * HWSZ] = v;
        }
    } else {
        const int gid  = (blockIdx.x - 32) * 256 + threadIdx.x;  // 0..524287
        const int quad = gid & 3;
        const int pix  = (gid >> 2) & (HWSZ - 1);
        const int bl   = gid >> 14;

        const float* src = images + (size_t)(bl * CC + quad * 4) * HWSZ + pix;
        float4 v;
        v.x = src[0 * HWSZ];
        v.y = src[1 * HWSZ];
        v.z = src[2 * HWSZ];
        v.w = src[3 * HWSZ];
        qp[((size_t)bl * 4 + quad) * HWSZ + pix] = v;
    }
}

// ---- main: block = (b, i, qs, pixel-quarter). For each j < i: stage the full
//      (b,j,qs) quad-plane into LDS (64 KB), then gather 4 bilinear corners per
//      pixel via ds_read_b128. Accumulate in registers (init = j==i identity
//      term), single coalesced store to out. No atomics, no partials.
//      Block-order pairing: blocks k and k+256 co-reside on a CU; their i's
//      sum to 15, so per-CU work is uniform (~15 j-stages). ----
__global__ __launch_bounds__(256) void gsp_main(
    const float2* __restrict__ cum2,   // (B, L, HW) float2
    const float4* __restrict__ qp,     // (B*L, 4, HW) float4 quad-planes
    float* __restrict__ out)           // (B, L, C, H, W)
{
    __shared__ float4 tile[HWSZ];      // 64 KB -> 2 blocks/CU

    const int e  = blockIdx.x >> 3;    // 0..63: (i, pixel-quarter) entry
    const int bq = blockIdx.x & 7;
    const int b  = bq >> 2;
    const int qs = bq & 3;

    // entries 0..31: i = 15..8 (heavy, first resident slot);
    // entries 32..63: i = 0..7 (light, second slot) -> co-resident sum = 15
    const int i     = (e < 32) ? (15 - (e >> 2)) : ((e - 32) >> 2);
    const int split = e & 3;
    const int px0   = split * 1024;

    const float2* cum_b = cum2 + (size_t)b * LL * HWSZ;
    const float4* qp_b  = qp + (size_t)b * LL * 4 * HWSZ;

    // init accumulators with the j == i identity term (exact integer centers)
    float4 acc[4];
    float2 ci[4];
    {
        const float4* ip = qp_b + ((size_t)i * 4 + qs) * HWSZ;
        #pragma unroll
        for (int k = 0; k < 4; ++k) {
            const int px = px0 + k * 256 + threadIdx.x;
            acc[k] = ip[px];
            ci[k]  = cum_b[(size_t)i * HWSZ + px];
        }
    }

    for (int j = 0; j < i; ++j) {
        // stage quad-plane (b, j, qs): contiguous 64 KB, coalesced
        const float4* src = qp_b + ((size_t)j * 4 + qs) * HWSZ;
        #pragma unroll
        for (int m = 0; m < 16; ++m)
            tile[m * 256 + threadIdx.x] = src[m * 256 + threadIdx.x];
        __syncthreads();

        #pragma unroll
        for (int k = 0; k < 4; ++k) {
            const int px = px0 + k * 256 + threadIdx.x;
            const int h = px >> 6;
            const int w = px & (WW - 1);

            const float2 cj = cum_b[(size_t)j * HWSZ + px];

            float gx = (w + 0.5f) * (2.0f / WW) - 1.0f + (ci[k].x - cj.x);
            float gy = (h + 0.5f) * (2.0f / HH) - 1.0f + (ci[k].y - cj.y);

            // gx = remainder(gx + 1, 2) - 1
            float tt = gx + 1.0f;
            tt = tt - floorf(tt * 0.5f) * 2.0f;
            gx = tt - 1.0f;

            const float ix = ((gx + 1.0f) * WW - 1.0f) * 0.5f;
            const float iy = ((gy + 1.0f) * HH - 1.0f) * 0.5f;
            const float x0f = floorf(ix);
            const float y0f = floorf(iy);
            const float fx = ix - x0f;
            const float fy = iy - y0f;
            const int x0 = (int)x0f;
            const int y0 = (int)y0f;
            const int x1 = x0 + 1;
            const int y1 = y0 + 1;

            const bool vx0 = (x0 >= 0) && (x0 < WW);
            const bool vx1 = (x1 >= 0) && (x1 < WW);
            const bool vy0 = (y0 >= 0) && (y0 < HH);
            const bool vy1 = (y1 >= 0) && (y1 < HH);

            const int cx0 = min(max(x0, 0), WW - 1);
            const int cx1 = min(max(x1, 0), WW - 1);
            const int cy0 = min(max(y0, 0), HH - 1);
            const int cy1 = min(max(y1, 0), HH - 1);

            const float w00 = ((vx0 && vy0) ? 1.0f : 0.0f) * (1.0f - fx) * (1.0f - fy);
            const float w01 = ((vx1 && vy0) ? 1.0f : 0.0f) * fx * (1.0f - fy);
            const float w10 = ((vx0 && vy1) ? 1.0f : 0.0f) * (1.0f - fx) * fy;
            const float w11 = ((vx1 && vy1) ? 1.0f : 0.0f) * fx * fy;

            const float4 v00 = tile[cy0 * WW + cx0];
            const float4 v01 = tile[cy0 * WW + cx1];
            const float4 v10 = tile[cy1 * WW + cx0];
            const float4 v11 = tile[cy1 * WW + cx1];

            acc[k].x += w00 * v00.x + w01 * v01.x + w10 * v10.x + w11 * v11.x;
            acc[k].y += w00 * v00.y + w01 * v01.y + w10 * v10.y + w11 * v11.y;
            acc[k].z += w00 * v00.z + w01 * v01.z + w10 * v10.z + w11 * v11.z;
            acc[k].w += w00 * v00.w + w01 * v01.w + w10 * v10.w + w11 * v11.w;
        }
        __syncthreads();
    }

    // single-writer coalesced store: out[(b,i), qs*4 + c, px]
    float* op = out + ((size_t)(b * LL + i) * CC + qs * 4) * HWSZ;
    #pragma unroll
    for (int k = 0; k < 4; ++k) {
        const int px = px0 + k * 256 + threadIdx.x;
        op[0 * HWSZ + px] = acc[k].x;
        op[1 * HWSZ + px] = acc[k].y;
        op[2 * HWSZ + px] = acc[k].z;
        op[3 * HWSZ + px] = acc[k].w;
    }
}

extern "C" void kernel_launch(void* const* d_in, const int* in_sizes, int n_in,
                              void* d_out, int out_size, void* d_ws, size_t ws_size,
                              hipStream_t stream) {
    const float* flows  = (const float*)d_in[0];
    const float* images = (const float*)d_in[1];
    float* out = (float*)d_out;
    float2* cum2 = (float2*)d_ws;
    float*  qp   = (float*)d_ws + CUM2_FLOATS;

    gsp_prep<<<32 + 2048, 256, 0, stream>>>(flows, images, cum2, (float4*)qp);

    gsp_main<<<512, 256, 0, stream>>>(cum2, (const float4*)qp, out);
}

// Round 12
// 85.970 us; speedup vs baseline: 1.1296x; 1.1296x over previous
//
#include <hip/hip_runtime.h>
#include <hip/hip_fp16.h>

#define BB 2
#define LL 16
#define CC 16
#define HH 64
#define WW 64
#define HWSZ (HH * WW)
#define NSEG 36   // per i: ceil(i/4) width-4 (padded) j-segments, i = 1..15

__device__ __constant__ int SEG_I[NSEG] = {
    1, 2, 3, 4,
    5, 5, 6, 6, 7, 7, 8, 8,
    9, 9, 9, 10, 10, 10, 11, 11, 11, 12, 12, 12,
    13, 13, 13, 13, 14, 14, 14, 14, 15, 15, 15, 15};
__device__ __constant__ int SEG_J0[NSEG] = {
    0, 0, 0, 0,
    0, 4, 0, 4, 0, 4, 0, 4,
    0, 4, 8, 0, 4, 8, 0, 4, 8, 0, 4, 8,
    0, 4, 8, 12, 0, 4, 8, 12, 0, 4, 8, 12};

__device__ __constant__ signed char NSEG_OF_I[LL] = {0,1,1,1,1,2,2,2,2,3,3,3,3,4,4,4};
__device__ __constant__ signed char SEG_OF_I[LL][4] = {
    {0,0,0,0},
    {0,0,0,0}, {1,0,0,0}, {2,0,0,0}, {3,0,0,0},
    {4,5,0,0}, {6,7,0,0}, {8,9,0,0}, {10,11,0,0},
    {12,13,14,0}, {15,16,17,0}, {18,19,20,0}, {21,22,23,0},
    {24,25,26,27}, {28,29,30,31}, {32,33,34,35}};

// ws layout (float units):
//   [0, 262144)          cum2 (B, L, HW) float2                      = 1 MB
//   [262144, 1310720)    h16  (B*L, HW, 2half) uint4 = 8 fp16 ch     = 4 MB
//   [1310720, 6029312)   partial (B, NSEG, HW, 4quad) float4         = 18 MB
#define CUM2_FLOATS (BB * LL * HWSZ * 2)
#define H16_FLOATS  (BB * LL * HWSZ * 8)   // 16 fp16 = 8 float-equivalents

__device__ __forceinline__ float2 cvt2(unsigned int u) {
    __half2 h = *reinterpret_cast<const __half2*>(&u);
    return __half22float2(h);
}

// ---- prep: cumsum -> cum2; NCHW fp32 -> NHWC fp16 (pixel = 32B, half = 16B) ----
__global__ __launch_bounds__(256) void gsp_prep(
    const float* __restrict__ flows,   // (B, L, 2, H, W)
    const float* __restrict__ images,  // (B, L, C, H, W)
    float2* __restrict__ cum2,         // (B, L, HW) float2
    uint4* __restrict__ h16)           // (B*L, HW, 2) uint4 (8 fp16 each)
{
    if (blockIdx.x < 32) {
        const int gid = blockIdx.x * 256 + threadIdx.x;   // 0..8191
        const int b   = gid >> 12;
        const int pix = gid & (HWSZ - 1);
        const float* fb = flows + (size_t)b * LL * 2 * HWSZ + pix;
        float vx[LL], vy[LL];
        #pragma unroll
        for (int l = 0; l < LL; ++l) {
            vx[l] = fb[(size_t)l * 2 * HWSZ];
            vy[l] = fb[(size_t)l * 2 * HWSZ + HWSZ];
        }
        #pragma unroll
        for (int l = 1; l < LL; ++l) { vx[l] += vx[l - 1]; vy[l] += vy[l - 1]; }
        float2* cb = cum2 + (size_t)b * LL * HWSZ + pix;
        #pragma unroll
        for (int l = 0; l < LL; ++l) {
            float2 v; v.x = vx[l]; v.y = vy[l];
            cb[(size_t)l * HWSZ] = v;
        }
    } else {
        const int gid  = (blockIdx.x - 32) * 256 + threadIdx.x;  // 0..262143
        const int half = gid & 1;
        const int pix  = (gid >> 1) & (HWSZ - 1);
        const int bl   = gid >> 13;

        const float* src = images + (size_t)(bl * CC + half * 8) * HWSZ + pix;
        unsigned short hs[8];
        #pragma unroll
        for (int m = 0; m < 8; ++m) {
            __half h = __float2half(src[(size_t)m * HWSZ]);
            hs[m] = *reinterpret_cast<unsigned short*>(&h);
        }
        uint4 v;
        v.x = (unsigned)hs[0] | ((unsigned)hs[1] << 16);
        v.y = (unsigned)hs[2] | ((unsigned)hs[3] << 16);
        v.z = (unsigned)hs[4] | ((unsigned)hs[5] << 16);
        v.w = (unsigned)hs[6] | ((unsigned)hs[7] << 16);
        h16[((size_t)bl * HWSZ + pix) * 2 + half] = v;
    }
}

// ---- pairs: j<i per width-4 segment. Lane = (pixel, 8ch-half); 16B fp16
//      gathers (half the lane-requests of the fp32 version). Partials fp32. ----
__global__ __launch_bounds__(256) void gsp_pairs(
    const float2* __restrict__ cum2,   // (B, L, HW) float2
    const uint4* __restrict__ h16,     // (B*L, HW, 2) uint4
    float4* __restrict__ partial)      // (B, NSEG, HW, 4quad) float4
{
    const int tile = blockIdx.x & 31;            // 32 tiles of 128 pixels
    const int seg  = (blockIdx.x >> 5) % NSEG;
    const int b    = blockIdx.x / (32 * NSEG);

    const int i    = SEG_I[seg];
    const int j0   = SEG_J0[seg];
    const int jmax = i - 1;

    const int half = threadIdx.x & 1;
    const int psub = threadIdx.x >> 1;           // 0..127
    const int pix  = tile * 128 + psub;          // 0..4095
    const int h = pix >> 6;
    const int w = pix & (WW - 1);

    const float2* cum_b = cum2 + (size_t)b * LL * HWSZ + pix;
    const uint4*  h16_b = h16 + (size_t)b * LL * HWSZ * 2;

    const float gxb = (w + 0.5f) * (2.0f / WW) - 1.0f;
    const float gyb = (h + 0.5f) * (2.0f / HH) - 1.0f;

    // phase 1: cum loads
    const float2 ci = cum_b[(size_t)i * HWSZ];
    int    jj[4];
    float2 cj[4];
    #pragma unroll
    for (int k = 0; k < 4; ++k) {
        jj[k] = min(j0 + k, jmax);
        cj[k] = cum_b[(size_t)jj[k] * HWSZ];
    }

    // phase 2: addresses + masks + fractions
    int   off[16];
    float fxk[4], fyk[4];
    float m00[4], m01[4], m10[4], m11[4];
    #pragma unroll
    for (int k = 0; k < 4; ++k) {
        float gx = gxb + (ci.x - cj[k].x);
        float gy = gyb + (ci.y - cj[k].y);

        // gx = remainder(gx + 1, 2) - 1
        float tt = gx + 1.0f;
        tt = tt - floorf(tt * 0.5f) * 2.0f;
        gx = tt - 1.0f;

        const float ix = ((gx + 1.0f) * WW - 1.0f) * 0.5f;
        const float iy = ((gy + 1.0f) * HH - 1.0f) * 0.5f;
        const float x0f = floorf(ix);
        const float y0f = floorf(iy);
        fxk[k] = ix - x0f;
        fyk[k] = iy - y0f;
        const int x0 = (int)x0f;
        const int y0 = (int)y0f;
        const int x1 = x0 + 1;
        const int y1 = y0 + 1;

        const bool vx0 = (x0 >= 0) && (x0 < WW);
        const bool vx1 = (x1 >= 0) && (x1 < WW);
        const bool vy0 = (y0 >= 0) && (y0 < HH);
        const bool vy1 = (y1 >= 0) && (y1 < HH);
        const float wpad = (j0 + k <= jmax) ? 1.0f : 0.0f;
        m00[k] = (vx0 && vy0) ? wpad : 0.0f;
        m01[k] = (vx1 && vy0) ? wpad : 0.0f;
        m10[k] = (vx0 && vy1) ? wpad : 0.0f;
        m11[k] = (vx1 && vy1) ? wpad : 0.0f;

        const int cx0 = min(max(x0, 0), WW - 1);
        const int cx1 = min(max(x1, 0), WW - 1);
        const int cy0 = min(max(y0, 0), HH - 1);
        const int cy1 = min(max(y1, 0), HH - 1);

        const int jbase = jj[k] * (HWSZ * 2) + half;   // uint4 units
        off[k * 4 + 0] = jbase + (cy0 * WW + cx0) * 2;
        off[k * 4 + 1] = jbase + (cy0 * WW + cx1) * 2;
        off[k * 4 + 2] = jbase + (cy1 * WW + cx0) * 2;
        off[k * 4 + 3] = jbase + (cy1 * WW + cx1) * 2;
    }

    // phase 3: 16 independent 16B gathers in flight
    uint4 v[16];
    #pragma unroll
    for (int m = 0; m < 16; ++m) v[m] = h16_b[off[m]];

    // phase 4: weights under the loads
    float wgt[16];
    #pragma unroll
    for (int k = 0; k < 4; ++k) {
        const float fx = fxk[k], fy = fyk[k];
        wgt[k * 4 + 0] = m00[k] * (1.0f - fx) * (1.0f - fy);
        wgt[k * 4 + 1] = m01[k] * fx * (1.0f - fy);
        wgt[k * 4 + 2] = m10[k] * (1.0f - fx) * fy;
        wgt[k * 4 + 3] = m11[k] * fx * fy;
    }

    // phase 5: unpack fp16 + FMA reduce (8 channels)
    float a0 = 0.f, a1 = 0.f, a2 = 0.f, a3 = 0.f;
    float a4 = 0.f, a5 = 0.f, a6 = 0.f, a7 = 0.f;
    #pragma unroll
    for (int m = 0; m < 16; ++m) {
        const float wm = wgt[m];
        const float2 p0 = cvt2(v[m].x);
        const float2 p1 = cvt2(v[m].y);
        const float2 p2 = cvt2(v[m].z);
        const float2 p3 = cvt2(v[m].w);
        a0 += wm * p0.x;  a1 += wm * p0.y;
        a2 += wm * p1.x;  a3 += wm * p1.y;
        a4 += wm * p2.x;  a5 += wm * p2.y;
        a6 += wm * p3.x;  a7 += wm * p3.y;
    }

    // store fp32 partial: two float4 quads (half -> quads 2h, 2h+1), coalesced
    float4* pp = partial + ((size_t)(b * NSEG + seg) * HWSZ + pix) * 4 + half * 2;
    float4 s0; s0.x = a0; s0.y = a1; s0.z = a2; s0.w = a3;
    float4 s1; s1.x = a4; s1.y = a5; s1.z = a6; s1.w = a7;
    pp[0] = s0;
    pp[1] = s1;
}

// ---- reduce: out = exact fp32 identity (from images) + segment partials ----
__global__ __launch_bounds__(256) void gsp_reduce(
    const float* __restrict__ images,    // (B, L, C, H, W) fp32
    const float4* __restrict__ partial,  // (B, NSEG, HW, 4) float4
    float* __restrict__ out)             // (B, L, C, H, W)
{
    const int gid  = blockIdx.x * 256 + threadIdx.x;  // 0..524287
    const int quad = gid & 3;
    const int pix  = (gid >> 2) & (HWSZ - 1);
    const int bl   = gid >> 14;
    const int b    = bl >> 4;
    const int i    = bl & 15;

    // j == i identity term, exact (integer pixel centers), fp32 source
    const float* ip = images + (size_t)(bl * CC + quad * 4) * HWSZ + pix;
    float4 s;
    s.x = ip[0 * HWSZ];
    s.y = ip[1 * HWSZ];
    s.z = ip[2 * HWSZ];
    s.w = ip[3 * HWSZ];

    const int n = NSEG_OF_I[i];
    for (int k = 0; k < n; ++k) {                     // wave-uniform trip count
        const int seg = SEG_OF_I[i][k];
        const float4 p = partial[((size_t)(b * NSEG + seg) * HWSZ + pix) * 4 + quad];
        s.x += p.x; s.y += p.y; s.z += p.z; s.w += p.w;
    }

    float* op = out + ((size_t)bl * CC + quad * 4) * HWSZ + pix;
    op[0 * HWSZ] = s.x;
    op[1 * HWSZ] = s.y;
    op[2 * HWSZ] = s.z;
    op[3 * HWSZ] = s.w;
}

extern "C" void kernel_launch(void* const* d_in, const int* in_sizes, int n_in,
                              void* d_out, int out_size, void* d_ws, size_t ws_size,
                              hipStream_t stream) {
    const float* flows  = (const float*)d_in[0];
    const float* images = (const float*)d_in[1];
    float* out = (float*)d_out;
    float2* cum2    = (float2*)d_ws;
    uint4*  h16     = (uint4*)((float*)d_ws + CUM2_FLOATS);
    float4* partial = (float4*)((float*)d_ws + CUM2_FLOATS + H16_FLOATS);

    gsp_prep<<<32 + 1024, 256, 0, stream>>>(flows, images, cum2, h16);

    const int grid = BB * NSEG * 32;                    // 2304 blocks
    gsp_pairs<<<grid, 256, 0, stream>>>(cum2, h16, partial);

    gsp_reduce<<<2048, 256, 0, stream>>>(images, partial, out);
}

// Round 13
// 78.947 us; speedup vs baseline: 1.2301x; 1.0889x over previous
//
#include <hip/hip_runtime.h>
#include <hip/hip_fp16.h>

#define BB 2
#define LL 16
#define CC 16
#define HH 64
#define WW 64
#define HWSZ (HH * WW)

// ws layout (float units):
//   [0, 262144)        cum2 (B, L, HW) float2                  = 1 MB
//   [262144, 1310720)  h16  (B*L, HW, 2half) uint4 (8 fp16)    = 4 MB
#define CUM2_FLOATS (BB * LL * HWSZ * 2)

__device__ __forceinline__ float2 cvt2(unsigned int u) {
    __half2 h = *reinterpret_cast<const __half2*>(&u);
    return __half22float2(h);
}

// ---- prep: cumsum -> cum2; NCHW fp32 -> NHWC fp16 (pixel = 32B, half = 16B) ----
__global__ __launch_bounds__(256) void gsp_prep(
    const float* __restrict__ flows,   // (B, L, 2, H, W)
    const float* __restrict__ images,  // (B, L, C, H, W)
    float2* __restrict__ cum2,         // (B, L, HW) float2
    uint4* __restrict__ h16)           // (B*L, HW, 2) uint4 (8 fp16 each)
{
    if (blockIdx.x < 32) {
        const int gid = blockIdx.x * 256 + threadIdx.x;   // 0..8191
        const int b   = gid >> 12;
        const int pix = gid & (HWSZ - 1);
        const float* fb = flows + (size_t)b * LL * 2 * HWSZ + pix;
        float vx[LL], vy[LL];
        #pragma unroll
        for (int l = 0; l < LL; ++l) {
            vx[l] = fb[(size_t)l * 2 * HWSZ];
            vy[l] = fb[(size_t)l * 2 * HWSZ + HWSZ];
        }
        #pragma unroll
        for (int l = 1; l < LL; ++l) { vx[l] += vx[l - 1]; vy[l] += vy[l - 1]; }
        float2* cb = cum2 + (size_t)b * LL * HWSZ + pix;
        #pragma unroll
        for (int l = 0; l < LL; ++l) {
            float2 v; v.x = vx[l]; v.y = vy[l];
            cb[(size_t)l * HWSZ] = v;
        }
    } else {
        const int gid  = (blockIdx.x - 32) * 256 + threadIdx.x;  // 0..262143
        const int half = gid & 1;
        const int pix  = (gid >> 1) & (HWSZ - 1);
        const int bl   = gid >> 13;

        const float* src = images + (size_t)(bl * CC + half * 8) * HWSZ + pix;
        unsigned short hs[8];
        #pragma unroll
        for (int m = 0; m < 8; ++m) {
            __half h = __float2half(src[(size_t)m * HWSZ]);
            hs[m] = *reinterpret_cast<unsigned short*>(&h);
        }
        uint4 v;
        v.x = (unsigned)hs[0] | ((unsigned)hs[1] << 16);
        v.y = (unsigned)hs[2] | ((unsigned)hs[3] << 16);
        v.z = (unsigned)hs[4] | ((unsigned)hs[5] << 16);
        v.w = (unsigned)hs[6] | ((unsigned)hs[7] << 16);
        h16[((size_t)bl * HWSZ + pix) * 2 + half] = v;
    }
}

// ---- main: block = (b, i, 64-px tile); lane = (px, xc, half). For each j < i:
//      the 4 lanes of one pixel load the CONTIGUOUS 64B covering both x-corners
//      and both channel-halves of a y-corner -> ~1.5 lines/pixel/instr (vs 2).
//      x-corner partial sums recombined with shfl_xor(2). Direct store to out;
//      no partials, no reduce kernel, no atomics. Heavy-i blocks dispatched first. ----
__global__ __launch_bounds__(256) void gsp_main(
    const float2* __restrict__ cum2,   // (B, L, HW) float2
    const uint4* __restrict__ h16,     // (B*L, HW, 2) uint4
    float* __restrict__ out)           // (B, L, C, H, W)
{
    const int idx  = blockIdx.x;                 // 2048 blocks, i descending
    const int i    = 15 - (idx >> 7);
    const int b    = (idx >> 6) & 1;
    const int tile = idx & 63;

    const int sub  = threadIdx.x & 3;            // (xc, half) within pixel
    const int half = sub & 1;
    const int xc   = sub >> 1;
    const int px   = tile * 64 + (threadIdx.x >> 2);
    const int h = px >> 6;
    const int w = px & (WW - 1);

    const float2* cum_b = cum2 + (size_t)b * LL * HWSZ + px;
    const uint4*  h16_b = h16 + (size_t)(b * LL) * HWSZ * 2;

    const float gxb = (w + 0.5f) * (2.0f / WW) - 1.0f;
    const float gyb = (h + 0.5f) * (2.0f / HH) - 1.0f;
    const float2 ci = cum_b[(size_t)i * HWSZ];

    float acc[8];
    #pragma unroll
    for (int m = 0; m < 8; ++m) acc[m] = 0.0f;

    for (int j = 0; j < i; ++j) {
        const float2 cj = cum_b[(size_t)j * HWSZ];

        float gx = gxb + (ci.x - cj.x);
        float gy = gyb + (ci.y - cj.y);

        // gx = remainder(gx + 1, 2) - 1
        float tt = gx + 1.0f;
        tt = tt - floorf(tt * 0.5f) * 2.0f;
        gx = tt - 1.0f;

        const float ix = ((gx + 1.0f) * WW - 1.0f) * 0.5f;
        const float iy = ((gy + 1.0f) * HH - 1.0f) * 0.5f;
        const float x0f = floorf(ix);
        const float y0f = floorf(iy);
        const float fx = ix - x0f;
        const float fy = iy - y0f;
        const int x0 = (int)x0f;
        const int y0 = (int)y0f;

        // this lane's x-corner
        const int  xr = x0 + xc;
        const bool vx = (xr >= 0) && (xr < WW);
        const int  cx = min(max(xr, 0), WW - 1);
        const float wx = (xc ? fx : (1.0f - fx)) * (vx ? 1.0f : 0.0f);

        // y-corners
        const int y1i = y0 + 1;
        const bool vy0 = (y0 >= 0) && (y0 < HH);
        const bool vy1 = (y1i >= 0) && (y1i < HH);
        const int cy0 = min(max(y0, 0), HH - 1);
        const int cy1 = min(max(y1i, 0), HH - 1);

        const uint4* jb = h16_b + (size_t)j * HWSZ * 2;
        const uint4 v0 = jb[(cy0 * WW + cx) * 2 + half];
        const uint4 v1 = jb[(cy1 * WW + cx) * 2 + half];

        const float w0 = wx * (1.0f - fy) * (vy0 ? 1.0f : 0.0f);
        const float w1 = wx * fy * (vy1 ? 1.0f : 0.0f);

        {
            const float2 p0 = cvt2(v0.x), p1 = cvt2(v0.y);
            const float2 p2 = cvt2(v0.z), p3 = cvt2(v0.w);
            acc[0] += w0 * p0.x;  acc[1] += w0 * p0.y;
            acc[2] += w0 * p1.x;  acc[3] += w0 * p1.y;
            acc[4] += w0 * p2.x;  acc[5] += w0 * p2.y;
            acc[6] += w0 * p3.x;  acc[7] += w0 * p3.y;
        }
        {
            const float2 p0 = cvt2(v1.x), p1 = cvt2(v1.y);
            const float2 p2 = cvt2(v1.z), p3 = cvt2(v1.w);
            acc[0] += w1 * p0.x;  acc[1] += w1 * p0.y;
            acc[2] += w1 * p1.x;  acc[3] += w1 * p1.y;
            acc[4] += w1 * p2.x;  acc[5] += w1 * p2.y;
            acc[6] += w1 * p3.x;  acc[7] += w1 * p3.y;
        }
    }

    // recombine the two x-corner partial sums (lanes differing in bit 1)
    #pragma unroll
    for (int m = 0; m < 8; ++m) acc[m] += __shfl_xor(acc[m], 2, 64);

    // this lane's output quad: q = half*2 + xc -> channels half*8 + xc*4 + 0..3
    float s0 = xc ? acc[4] : acc[0];
    float s1 = xc ? acc[5] : acc[1];
    float s2 = xc ? acc[6] : acc[2];
    float s3 = xc ? acc[7] : acc[3];

    // identity term (j == i, exact integer pixel centers), fp16 source
    {
        const uint2* h2 = (const uint2*)h16;
        const uint2 idv = h2[(((size_t)(b * LL + i) * HWSZ + px) * 2 + half) * 2 + xc];
        const float2 p0 = cvt2(idv.x), p1 = cvt2(idv.y);
        s0 += p0.x; s1 += p0.y; s2 += p1.x; s3 += p1.y;
    }

    const int q = half * 2 + xc;
    float* op = out + ((size_t)(b * LL + i) * CC + q * 4) * HWSZ + px;
    op[0 * HWSZ] = s0;
    op[1 * HWSZ] = s1;
    op[2 * HWSZ] = s2;
    op[3 * HWSZ] = s3;
}

extern "C" void kernel_launch(void* const* d_in, const int* in_sizes, int n_in,
                              void* d_out, int out_size, void* d_ws, size_t ws_size,
                              hipStream_t stream) {
    const float* flows  = (const float*)d_in[0];
    const float* images = (const float*)d_in[1];
    float* out = (float*)d_out;
    float2* cum2 = (float2*)d_ws;
    uint4*  h16  = (uint4*)((float*)d_ws + CUM2_FLOATS);

    gsp_prep<<<32 + 1024, 256, 0, stream>>>(flows, images, cum2, h16);

    gsp_main<<<2048, 256, 0, stream>>>(cum2, h16, out);
}

// Round 14
// 76.973 us; speedup vs baseline: 1.2616x; 1.0256x over previous
//
#include <hip/hip_runtime.h>
#include <hip/hip_fp16.h>

#define BB 2
#define LL 16
#define CC 16
#define HH 64
#define WW 64
#define HWSZ (HH * WW)

__device__ __forceinline__ float2 cvt2(unsigned int u) {
    __half2 h = *reinterpret_cast<const __half2*>(&u);
    return __half22float2(h);
}

// ---- prep: NCHW fp32 -> NHWC fp16 (pixel = 32B; 16B per 8-ch half) ----
__global__ __launch_bounds__(256) void gsp_prep(
    const float* __restrict__ images,  // (B, L, C, H, W)
    uint4* __restrict__ h16)           // (B*L, HW, 2) uint4 (8 fp16 each)
{
    const int gid  = blockIdx.x * 256 + threadIdx.x;  // 0..262143
    const int half = gid & 1;
    const int pix  = (gid >> 1) & (HWSZ - 1);
    const int bl   = gid >> 13;

    const float* src = images + (size_t)(bl * CC + half * 8) * HWSZ + pix;
    unsigned short hs[8];
    #pragma unroll
    for (int m = 0; m < 8; ++m) {
        __half h = __float2half(src[(size_t)m * HWSZ]);
        hs[m] = *reinterpret_cast<unsigned short*>(&h);
    }
    uint4 v;
    v.x = (unsigned)hs[0] | ((unsigned)hs[1] << 16);
    v.y = (unsigned)hs[2] | ((unsigned)hs[3] << 16);
    v.z = (unsigned)hs[4] | ((unsigned)hs[5] << 16);
    v.w = (unsigned)hs[6] | ((unsigned)hs[7] << 16);
    h16[((size_t)bl * HWSZ + pix) * 2 + half] = v;
}

// ---- main: block = (b, i, 64-px tile); lane = (px, xc, half). Per-thread
//      register cumsum of flows (no cum2 workspace). j-loop fully unrolled
//      (wave-uniform guards) so all gather loads can be hoisted/overlapped.
//      4 lanes of a pixel load contiguous 64B (both x-corners x both halves
//      of one y-corner); x-partials recombined via shfl_xor(2). ----
__global__ __launch_bounds__(256) void gsp_main(
    const float* __restrict__ flows,   // (B, L, 2, H, W)
    const uint4* __restrict__ h16,     // (B*L, HW, 2) uint4
    float* __restrict__ out)           // (B, L, C, H, W)
{
    const int idx  = blockIdx.x;                 // 2048 blocks, heavy i first
    const int i    = 15 - (idx >> 7);
    const int b    = (idx >> 6) & 1;
    const int tile = idx & 63;

    const int sub  = threadIdx.x & 3;            // (xc, half) within pixel
    const int half = sub & 1;
    const int xc   = sub >> 1;
    const int px   = tile * 64 + (threadIdx.x >> 2);
    const int h = px >> 6;
    const int w = px & (WW - 1);

    // per-thread cumsum of flows at this pixel (all 16 loads independent)
    float cx16[LL], cy16[LL];
    {
        const float* fb = flows + (size_t)b * LL * 2 * HWSZ + px;
        #pragma unroll
        for (int l = 0; l < LL; ++l) {
            cx16[l] = fb[(size_t)l * 2 * HWSZ];
            cy16[l] = fb[(size_t)l * 2 * HWSZ + HWSZ];
        }
        #pragma unroll
        for (int l = 1; l < LL; ++l) { cx16[l] += cx16[l - 1]; cy16[l] += cy16[l - 1]; }
    }

    const uint4* h16_b = h16 + (size_t)(b * LL) * HWSZ * 2;

    const float gxb = (w + 0.5f) * (2.0f / WW) - 1.0f;
    const float gyb = (h + 0.5f) * (2.0f / HH) - 1.0f;

    float cix = 0.0f, ciy = 0.0f;
    #pragma unroll
    for (int l = 0; l < LL; ++l) { if (l == i) { cix = cx16[l]; ciy = cy16[l]; } }

    float acc[8];
    #pragma unroll
    for (int m = 0; m < 8; ++m) acc[m] = 0.0f;

    #pragma unroll
    for (int j = 0; j < LL - 1; ++j) {
        if (j < i) {                             // wave-uniform guard
            float gx = gxb + (cix - cx16[j]);
            float gy = gyb + (ciy - cy16[j]);

            // gx = remainder(gx + 1, 2) - 1
            float tt = gx + 1.0f;
            tt = tt - floorf(tt * 0.5f) * 2.0f;
            gx = tt - 1.0f;

            const float ix = ((gx + 1.0f) * WW - 1.0f) * 0.5f;
            const float iy = ((gy + 1.0f) * HH - 1.0f) * 0.5f;
            const float x0f = floorf(ix);
            const float y0f = floorf(iy);
            const float fx = ix - x0f;
            const float fy = iy - y0f;
            const int x0 = (int)x0f;
            const int y0 = (int)y0f;

            // this lane's x-corner
            const int  xr = x0 + xc;
            const bool vx = (xr >= 0) && (xr < WW);
            const int  cx = min(max(xr, 0), WW - 1);
            const float wx = (xc ? fx : (1.0f - fx)) * (vx ? 1.0f : 0.0f);

            // y-corners
            const int y1i = y0 + 1;
            const bool vy0 = (y0 >= 0) && (y0 < HH);
            const bool vy1 = (y1i >= 0) && (y1i < HH);
            const int cy0 = min(max(y0, 0), HH - 1);
            const int cy1 = min(max(y1i, 0), HH - 1);

            const uint4* jb = h16_b + (size_t)j * HWSZ * 2;
            const uint4 v0 = jb[(cy0 * WW + cx) * 2 + half];
            const uint4 v1 = jb[(cy1 * WW + cx) * 2 + half];

            const float w0 = wx * (1.0f - fy) * (vy0 ? 1.0f : 0.0f);
            const float w1 = wx * fy * (vy1 ? 1.0f : 0.0f);

            {
                const float2 p0 = cvt2(v0.x), p1 = cvt2(v0.y);
                const float2 p2 = cvt2(v0.z), p3 = cvt2(v0.w);
                acc[0] += w0 * p0.x;  acc[1] += w0 * p0.y;
                acc[2] += w0 * p1.x;  acc[3] += w0 * p1.y;
                acc[4] += w0 * p2.x;  acc[5] += w0 * p2.y;
                acc[6] += w0 * p3.x;  acc[7] += w0 * p3.y;
            }
            {
                const float2 p0 = cvt2(v1.x), p1 = cvt2(v1.y);
                const float2 p2 = cvt2(v1.z), p3 = cvt2(v1.w);
                acc[0] += w1 * p0.x;  acc[1] += w1 * p0.y;
                acc[2] += w1 * p1.x;  acc[3] += w1 * p1.y;
                acc[4] += w1 * p2.x;  acc[5] += w1 * p2.y;
                acc[6] += w1 * p3.x;  acc[7] += w1 * p3.y;
            }
        }
    }

    // recombine the two x-corner partial sums (lanes differing in bit 1)
    #pragma unroll
    for (int m = 0; m < 8; ++m) acc[m] += __shfl_xor(acc[m], 2, 64);

    // this lane's output quad: q = half*2 + xc -> channels q*4 .. q*4+3
    float s0 = xc ? acc[4] : acc[0];
    float s1 = xc ? acc[5] : acc[1];
    float s2 = xc ? acc[6] : acc[2];
    float s3 = xc ? acc[7] : acc[3];

    // identity term (j == i, exact integer pixel centers), fp16 source
    {
        const uint2* h2 = (const uint2*)h16;
        const uint2 idv = h2[(((size_t)(b * LL + i) * HWSZ + px) * 2 + half) * 2 + xc];
        const float2 p0 = cvt2(idv.x), p1 = cvt2(idv.y);
        s0 += p0.x; s1 += p0.y; s2 += p1.x; s3 += p1.y;
    }

    const int q = half * 2 + xc;
    float* op = out + ((size_t)(b * LL + i) * CC + q * 4) * HWSZ + px;
    op[0 * HWSZ] = s0;
    op[1 * HWSZ] = s1;
    op[2 * HWSZ] = s2;
    op[3 * HWSZ] = s3;
}

extern "C" void kernel_launch(void* const* d_in, const int* in_sizes, int n_in,
                              void* d_out, int out_size, void* d_ws, size_t ws_size,
                              hipStream_t stream) {
    const float* flows  = (const float*)d_in[0];
    const float* images = (const float*)d_in[1];
    float* out = (float*)d_out;
    uint4* h16 = (uint4*)d_ws;                         // 4 MB

    gsp_prep<<<1024, 256, 0, stream>>>(images, h16);

    gsp_main<<<2048, 256, 0, stream>>>(flows, h16, out);
}